// Round 10
// baseline (28240.964 us; speedup 1.0000x reference)
//
#include <hip/hip_runtime.h>
#include <math.h>

#define TT 2048
#define BB 64
#define II 64
#define HH 512
#define OO 32
#define OCC 8
#define QS 128   // k/h slice per WG (4-way split)

// d_out layout: output [T,B,32] | output_ctx [T,B,8] | rate_all [T,B,512]
#define OUT1_OFF ((size_t)TT * BB * OO)
#define RATE_OFF (OUT1_OFF + (size_t)TT * BB * OCC)

// d_ws: P2[B][4][2][HH] u64 tagged pairs = 2 MB
#define P2_QWORDS ((size_t)BB * 4 * 2 * HH)

// ---------------------------------------------------------------------------
// Recurrent scan, 4-way k-split, prefold FUSED, tagged-data cross-WG sync.
// WG (q,b) at bid=q*64+b owns k-slice AND h-slice [128q,128q+128).
// 1024 threads: g=tid>>7 -> 16 k-rows, ht=tid&127 -> h-cols 4ht..4ht+3.
// Publish: (tag=t+1)<<32 | bits(partial) as ONE relaxed 64-bit agent atomic
// -> tag travels atomically with data: no flag, no pre-flag vmcnt drain, no
// acquire hop. Consumers (contiguous band tid in [128q,128q+128)) poll their
// 3 remote words directly. DEADLOCK RULE (round 8): each thread's publish
// store PRECEDES its polls in program order -> store issues regardless of
// spins; no store is gated behind a poll. Overwrite race: parity dbuf + the
// round-4 data-dependency chain (peer can only reach its t+2 publish after
// consuming t, which is after our t-read completed). Stale tags across graph
// replays: P2 memset to 0 each launch (tags are 1..2048, 0 never matches).
// ---------------------------------------------------------------------------
__global__ __launch_bounds__(1024) void rnn_scan10(
    const float* __restrict__ x,       // [T,B,I]
    const float* __restrict__ rate0,   // [B,H]
    const float* __restrict__ noise,   // [T,B,H]
    const float* __restrict__ Wh,      // [H,H] row-major
    const float* __restrict__ Wi,      // [H,I]
    const float* __restrict__ bi,
    const float* __restrict__ bh,
    float* __restrict__ rate_out,      // [T,B,H]
    unsigned long long* P2)            // [B][4][2][HH] tagged pairs
{
    __shared__ float st[QS];               // own state slice
    __shared__ float parts[8 * HH];        // per-g partials (16 KB)
    __shared__ float wi_lds[QS][II + 4];   // Wi rows of own h-slice (+4: 8-way not 32-way)
    __shared__ float xbuf[II];             // x_t

    const int bid = blockIdx.x;
    const int q   = bid >> 6;              // quarter 0..3
    const int b   = bid & 63;              // batch
    const int tid = threadIdx.x;
    const int g   = tid >> 7;              // 0..7 -> 16 k-rows each
    const int ht  = tid & 127;
    const int h4  = 4 * ht;
    const int kq  = q * QS + g * 16;

    const double SIG = 1.5 / sqrt(512.0);
    const float  NS  = (float)sqrt(2.0 * SIG * SIG / 0.1);

    // Wh weights fully VGPR-resident: wreg[m] = W^T[kq+m][h4..h4+3]
    float4 wreg[16];
    #pragma unroll
    for (int m = 0; m < 16; ++m) {
        wreg[m].x = Wh[(size_t)(h4 + 0) * HH + kq + m];
        wreg[m].y = Wh[(size_t)(h4 + 1) * HH + kq + m];
        wreg[m].z = Wh[(size_t)(h4 + 2) * HH + kq + m];
        wreg[m].w = Wh[(size_t)(h4 + 3) * HH + kq + m];
    }

    // Wi rows for own h-slice -> LDS (one-time)
    for (int i = tid; i < QS * (II / 4); i += 1024) {
        int l = i >> 4, c4 = (i & 15) * 4;
        *(float4*)&wi_lds[l][c4] = *(const float4*)&Wi[(size_t)(q * QS + l) * II + c4];
    }

    const bool inband = (tid >= q * QS) && (tid < q * QS + QS);
    const int  l      = tid - q * QS;      // local h index when inband
    float rf = 0.f, bsum = 0.f;
    if (inband) {
        rf   = rate0[b * HH + tid];
        bsum = bi[tid] + bh[tid];
    }
    if (tid < QS) st[tid] = rate0[b * HH + q * QS + tid];
    __syncthreads();

    for (int t = 0; t < TT; ++t) {
        const int par = t & 1;
        const size_t row = ((size_t)t * BB + b) * HH;

        // stage x_t; early noise load (consumed after B1 / during poll window)
        if (tid < 16)
            *(float4*)&xbuf[4 * tid] = *(const float4*)&x[((size_t)t * BB + b) * II + 4 * tid];
        float nz = 0.f;
        if (inband) nz = noise[row + tid];

        // ---- dot: this thread's 4 h-cols over its 16 k-rows (st broadcast)
        float a0 = 0.f, a1 = 0.f, a2 = 0.f, a3 = 0.f;
        #pragma unroll
        for (int mm = 0; mm < 4; ++mm) {
            float4 s4 = *(const float4*)&st[g * 16 + 4 * mm];
            a0 += wreg[4*mm].x*s4.x + wreg[4*mm+1].x*s4.y + wreg[4*mm+2].x*s4.z + wreg[4*mm+3].x*s4.w;
            a1 += wreg[4*mm].y*s4.x + wreg[4*mm+1].y*s4.y + wreg[4*mm+2].y*s4.z + wreg[4*mm+3].y*s4.w;
            a2 += wreg[4*mm].z*s4.x + wreg[4*mm+1].z*s4.y + wreg[4*mm+2].z*s4.z + wreg[4*mm+3].z*s4.w;
            a3 += wreg[4*mm].w*s4.x + wreg[4*mm+1].w*s4.y + wreg[4*mm+2].w*s4.z + wreg[4*mm+3].w*s4.w;
        }
        *(float4*)&parts[g * HH + h4] = make_float4(a0, a1, a2, a3);
        __syncthreads();                      // B1: parts + xbuf ready

        // ---- reduce over g, publish tagged partial (stores precede polls!)
        float s = 0.f;
        if (tid < HH) {
            #pragma unroll
            for (int p = 0; p < 8; ++p) s += parts[p * HH + tid];
            unsigned long long w =
                ((unsigned long long)(unsigned)(t + 1) << 32) | __float_as_uint(s);
            __hip_atomic_store(&P2[(((size_t)b * 4 + q) * 2 + par) * HH + tid], w,
                               __ATOMIC_RELAXED, __HIP_MEMORY_SCOPE_AGENT);
        }

        // ---- consumers: pre compute (hides under publish flight) + poll + update
        if (inband) {
            float pre = bsum + NS * nz;
            #pragma unroll
            for (int c4 = 0; c4 < II; c4 += 4) {
                float4 wv = *(const float4*)&wi_lds[l][c4];
                float4 xv = *(const float4*)&xbuf[c4];
                pre += wv.x * xv.x + wv.y * xv.y + wv.z * xv.z + wv.w * xv.w;
            }

            const unsigned tag = (unsigned)(t + 1);
            unsigned long long* r0 = &P2[(((size_t)b * 4 + ((q + 1) & 3)) * 2 + par) * HH + tid];
            unsigned long long* r1 = &P2[(((size_t)b * 4 + ((q + 2) & 3)) * 2 + par) * HH + tid];
            unsigned long long* r2 = &P2[(((size_t)b * 4 + ((q + 3) & 3)) * 2 + par) * HH + tid];
            float v0 = 0.f, v1 = 0.f, v2 = 0.f;
            bool d0 = false, d1 = false, d2 = false;
            while (!(d0 && d1 && d2)) {
                if (!d0) {
                    unsigned long long u = __hip_atomic_load(r0, __ATOMIC_RELAXED, __HIP_MEMORY_SCOPE_AGENT);
                    if ((unsigned)(u >> 32) == tag) { v0 = __uint_as_float((unsigned)u); d0 = true; }
                }
                if (!d1) {
                    unsigned long long u = __hip_atomic_load(r1, __ATOMIC_RELAXED, __HIP_MEMORY_SCOPE_AGENT);
                    if ((unsigned)(u >> 32) == tag) { v1 = __uint_as_float((unsigned)u); d1 = true; }
                }
                if (!d2) {
                    unsigned long long u = __hip_atomic_load(r2, __ATOMIC_RELAXED, __HIP_MEMORY_SCOPE_AGENT);
                    if ((unsigned)(u >> 32) == tag) { v2 = __uint_as_float((unsigned)u); d2 = true; }
                }
            }

            float tot = pre + s + v0 + v1 + v2;   // same order as rounds 4-9
            rf = 0.9f * rf + 0.1f * tanhf(tot);
            rate_out[row + tid] = rf;
            st[l] = rf;
        }
        __syncthreads();                      // B4: st ready for next dot
    }
}

// ---------------------------------------------------------------------------
// Readouts: 16 rows per 512-thread block, rows staged in LDS, float4 dots.
// ---------------------------------------------------------------------------
__global__ __launch_bounds__(512) void readout(
    const float* __restrict__ rate_all,
    const float* __restrict__ Wo,  const float* __restrict__ bo,
    const float* __restrict__ Woc, const float* __restrict__ boc,
    float* __restrict__ out, float* __restrict__ outc)
{
    __shared__ float rbuf[16][HH];
    const int tid  = threadIdx.x;
    const size_t row0 = (size_t)blockIdx.x * 16;

    for (int i = tid; i < 16 * (HH / 4); i += 512) {
        int r = i >> 7, c = (i & 127) * 4;
        *(float4*)&rbuf[r][c] = *(const float4*)&rate_all[(row0 + r) * HH + c];
    }
    __syncthreads();

    {
        int r = tid >> 5, o = tid & 31;
        const float* w = Wo + (size_t)o * HH;
        float acc = 0.f;
        #pragma unroll 4
        for (int h = 0; h < HH; h += 4) {
            float4 rv = *(const float4*)&rbuf[r][h];
            float4 wv = *(const float4*)&w[h];
            acc += rv.x * wv.x + rv.y * wv.y + rv.z * wv.z + rv.w * wv.w;
        }
        out[(row0 + r) * OO + o] = acc + bo[o];
    }
    if (tid < 128) {
        int r = tid >> 3, oc = tid & 7;
        const float* w = Woc + (size_t)oc * HH;
        float acc = 0.f;
        #pragma unroll 4
        for (int h = 0; h < HH; h += 4) {
            float4 rv = *(const float4*)&rbuf[r][h];
            float4 wv = *(const float4*)&w[h];
            acc += rv.x * wv.x + rv.y * wv.y + rv.z * wv.z + rv.w * wv.w;
        }
        outc[(row0 + r) * OCC + oc] = acc + boc[oc];
    }
}

// ---------------------------------------------------------------------------
extern "C" void kernel_launch(void* const* d_in, const int* in_sizes, int n_in,
                              void* d_out, int out_size, void* d_ws, size_t ws_size,
                              hipStream_t stream)
{
    const float* x     = (const float*)d_in[0];
    const float* rate0 = (const float*)d_in[1];
    const float* noise = (const float*)d_in[2];
    const float* Wi    = (const float*)d_in[3];
    const float* bi    = (const float*)d_in[4];
    const float* Wh    = (const float*)d_in[5];
    const float* bh    = (const float*)d_in[6];
    const float* Wo    = (const float*)d_in[7];
    const float* bo    = (const float*)d_in[8];
    const float* Woc   = (const float*)d_in[9];
    const float* boc   = (const float*)d_in[10];

    float* out   = (float*)d_out;
    float* rateb = out + RATE_OFF;
    unsigned long long* P2 = (unsigned long long*)d_ws;   // 2 MB

    // clear stale tags from previous replay (tags 1..2048; 0 never matches)
    hipMemsetAsync(P2, 0, P2_QWORDS * sizeof(unsigned long long), stream);
    rnn_scan10<<<4 * BB, 1024, 0, stream>>>(x, rate0, noise, Wh, Wi, bi, bh,
                                            rateb, P2);
    readout<<<TT * BB / 16, 512, 0, stream>>>(rateb, Wo, bo, Woc, boc,
                                              out, out + OUT1_OFF);
}

// Round 11
// 5556.467 us; speedup vs baseline: 5.0825x; 5.0825x over previous
//
#include <hip/hip_runtime.h>
#include <math.h>

#define TT 2048
#define BB 64
#define II 64
#define HH 512
#define OO 32
#define OCC 8
#define QS 128   // k/h slice per WG (4-way split)

// d_out layout: output [T,B,32] | output_ctx [T,B,8] | rate_all [T,B,512]
#define OUT1_OFF ((size_t)TT * BB * OO)
#define RATE_OFF (OUT1_OFF + (size_t)TT * BB * OCC)

// d_ws layout: P[B][4][2][HH] floats (1 MB) | flags int[B*4*16] @ 1 MB
#define FLAG_BYTE_OFF ((size_t)1 << 20)
#define FLAG_BYTES (BB * 4 * 16 * sizeof(int))

// ---------------------------------------------------------------------------
// Recurrent scan, 4-way k-split, prefold FUSED, round-9 flag sync (proven
// 4.06 ms). WG (q,b) at bid=q*64+b owns k-slice AND h-slice [128q,128q+128).
// 1024 threads: g=tid>>7 -> 16 k-rows, ht=tid&127 -> h-cols 4ht..4ht+3.
// SYNC RULES (hard-won):
//  - r8 hang: flag store and peer polls in DIFFERENT waves (tid 0 stores;
//    tid 64/128/192 poll). No store gated behind a poll.
//  - r10 storm: poll traffic must be O(pollers)=3/WG, not O(consumers).
//    Consumers read remote P exactly once, after B3.
//  - r4 storm: agent-scope RELAXED atomics only (IF-direct, no cache
//    maintenance). Ordering via B2's per-wave vmcnt(0) drain before the
//    flag store (in-order wave issue).
// Parity-double-buffered P; race-freedom by the r4 flag-chain argument.
// Fused prefold: pre = (bi+bh) + NS*noise + x_t . Wi[h,:], computed between
// flag store and B3 -> hides entirely under the poll window. Same summation
// order as the standalone prefold (validated absmax 0.0625 in r10).
// ---------------------------------------------------------------------------
__global__ __launch_bounds__(1024) void rnn_scan11(
    const float* __restrict__ x,       // [T,B,I]
    const float* __restrict__ rate0,   // [B,H]
    const float* __restrict__ noise,   // [T,B,H]
    const float* __restrict__ Wh,      // [H,H] row-major
    const float* __restrict__ Wi,      // [H,I]
    const float* __restrict__ bi,
    const float* __restrict__ bh,
    float* __restrict__ rate_out,      // [T,B,H]
    float* P,                          // [B][4][2][HH]
    int* flags)                        // [B*4*16]
{
    __shared__ float  st[QS];          // own state slice
    __shared__ float  parts[8 * HH];   // per-g partials (16 KB)
    __shared__ float4 wi4[II / 4][QS]; // Wi slice, [c4][l]: lane-consecutive reads
    __shared__ float4 xbuf4[II / 4];   // x_t (broadcast reads)

    const int bid = blockIdx.x;
    const int q   = bid >> 6;          // quarter 0..3
    const int b   = bid & 63;          // batch
    const int tid = threadIdx.x;
    const int g   = tid >> 7;          // 0..7 -> 16 k-rows each
    const int ht  = tid & 127;
    const int h4  = 4 * ht;
    const int kq  = q * QS + g * 16;

    const double SIG = 1.5 / sqrt(512.0);
    const float  NS  = (float)sqrt(2.0 * SIG * SIG / 0.1);

    // Wh weights fully VGPR-resident: wreg[m] = W^T[kq+m][h4..h4+3]
    float4 wreg[16];
    #pragma unroll
    for (int m = 0; m < 16; ++m) {
        wreg[m].x = Wh[(size_t)(h4 + 0) * HH + kq + m];
        wreg[m].y = Wh[(size_t)(h4 + 1) * HH + kq + m];
        wreg[m].z = Wh[(size_t)(h4 + 2) * HH + kq + m];
        wreg[m].w = Wh[(size_t)(h4 + 3) * HH + kq + m];
    }

    // Wi rows of own h-slice -> LDS (one-time; global-coalesced in i)
    for (int i = tid; i < QS * (II / 4); i += 1024) {
        int l = i >> 4, c4 = i & 15;
        wi4[c4][l] = *(const float4*)&Wi[(size_t)(q * QS + l) * II + 4 * c4];
    }

    const bool inband = (tid >= q * QS) && (tid < q * QS + QS);
    const int  l      = tid - q * QS;  // local h index when inband
    float rf = 0.f, bsum = 0.f;
    if (inband) {
        rf   = rate0[b * HH + tid];
        bsum = bi[tid] + bh[tid];
    }
    if (tid < QS) st[tid] = rate0[b * HH + q * QS + tid];
    int* myflag = &flags[(b * 4 + q) * 16];
    __syncthreads();

    for (int t = 0; t < TT; ++t) {
        const int par = t & 1;
        const size_t row = ((size_t)t * BB + b) * HH;

        // stage x_t (read at pre-compute, after B2; next overwrite after B4)
        if (tid < II / 4)
            xbuf4[tid] = *(const float4*)&x[((size_t)t * BB + b) * II + 4 * tid];
        float nz = 0.f;
        if (inband) nz = noise[row + tid];    // early; hides under dot

        // ---- dot: this thread's 4 h-cols over its 16 k-rows (st broadcast)
        float a0 = 0.f, a1 = 0.f, a2 = 0.f, a3 = 0.f;
        #pragma unroll
        for (int mm = 0; mm < 4; ++mm) {
            float4 s4 = *(const float4*)&st[g * 16 + 4 * mm];
            a0 += wreg[4*mm].x*s4.x + wreg[4*mm+1].x*s4.y + wreg[4*mm+2].x*s4.z + wreg[4*mm+3].x*s4.w;
            a1 += wreg[4*mm].y*s4.x + wreg[4*mm+1].y*s4.y + wreg[4*mm+2].y*s4.z + wreg[4*mm+3].y*s4.w;
            a2 += wreg[4*mm].z*s4.x + wreg[4*mm+1].z*s4.y + wreg[4*mm+2].z*s4.z + wreg[4*mm+3].z*s4.w;
            a3 += wreg[4*mm].w*s4.x + wreg[4*mm+1].w*s4.y + wreg[4*mm+2].w*s4.z + wreg[4*mm+3].w*s4.w;
        }
        *(float4*)&parts[g * HH + h4] = make_float4(a0, a1, a2, a3);
        __syncthreads();                      // B1: parts + xbuf ready

        // ---- reduce over g, publish partial to IF
        float s = 0.f;
        if (tid < HH) {
            #pragma unroll
            for (int p = 0; p < 8; ++p) s += parts[p * HH + tid];
            __hip_atomic_store(&P[(((size_t)b * 4 + q) * 2 + par) * HH + tid], s,
                               __ATOMIC_RELAXED, __HIP_MEMORY_SCOPE_AGENT);
        }
        __syncthreads();                      // B2: all waves vmcnt(0) -> P at IF

        // ---- flag publish (wave 0, immediately after B2)
        if (tid == 0)
            __hip_atomic_store(myflag, t + 1, __ATOMIC_RELAXED,
                               __HIP_MEMORY_SCOPE_AGENT);

        // ---- fused prefold: hides under the poll window
        float pre = 0.f;
        if (inband) {
            pre = bsum + NS * nz;
            #pragma unroll
            for (int c4 = 0; c4 < II / 4; ++c4) {
                float4 wv = wi4[c4][l];
                float4 xv = xbuf4[c4];
                pre += wv.x * xv.x + wv.y * xv.y + wv.z * xv.z + wv.w * xv.w;
            }
        }

        // ---- peer polls (waves 1..3; store above precedes polls -- r8 rule)
        if (tid == 64 || tid == 128 || tid == 192) {
            int* f = &flags[(b * 4 + ((q + (tid >> 6)) & 3)) * 16];
            while (__hip_atomic_load(f, __ATOMIC_RELAXED,
                                     __HIP_MEMORY_SCOPE_AGENT) < t + 1) {}
        }
        __syncthreads();                      // B3: peers' P published

        // ---- consume: own-slice update (consumer reuses its own s)
        if (inband) {
            float tot = pre + s;
            #pragma unroll
            for (int j = 1; j < 4; ++j) {
                const int pj = (q + j) & 3;
                tot += __hip_atomic_load(
                    &P[(((size_t)b * 4 + pj) * 2 + par) * HH + tid],
                    __ATOMIC_RELAXED, __HIP_MEMORY_SCOPE_AGENT);
            }
            rf = 0.9f * rf + 0.1f * tanhf(tot);
            rate_out[row + tid] = rf;
            st[l] = rf;
        }
        __syncthreads();                      // B4: st ready for next dot
    }
}

// ---------------------------------------------------------------------------
// Readouts: 16 rows per 512-thread block, rows staged in LDS, float4 dots.
// ---------------------------------------------------------------------------
__global__ __launch_bounds__(512) void readout(
    const float* __restrict__ rate_all,
    const float* __restrict__ Wo,  const float* __restrict__ bo,
    const float* __restrict__ Woc, const float* __restrict__ boc,
    float* __restrict__ out, float* __restrict__ outc)
{
    __shared__ float rbuf[16][HH];
    const int tid  = threadIdx.x;
    const size_t row0 = (size_t)blockIdx.x * 16;

    for (int i = tid; i < 16 * (HH / 4); i += 512) {
        int r = i >> 7, c = (i & 127) * 4;
        *(float4*)&rbuf[r][c] = *(const float4*)&rate_all[(row0 + r) * HH + c];
    }
    __syncthreads();

    {
        int r = tid >> 5, o = tid & 31;
        const float* w = Wo + (size_t)o * HH;
        float acc = 0.f;
        #pragma unroll 4
        for (int h = 0; h < HH; h += 4) {
            float4 rv = *(const float4*)&rbuf[r][h];
            float4 wv = *(const float4*)&w[h];
            acc += rv.x * wv.x + rv.y * wv.y + rv.z * wv.z + rv.w * wv.w;
        }
        out[(row0 + r) * OO + o] = acc + bo[o];
    }
    if (tid < 128) {
        int r = tid >> 3, oc = tid & 7;
        const float* w = Woc + (size_t)oc * HH;
        float acc = 0.f;
        #pragma unroll 4
        for (int h = 0; h < HH; h += 4) {
            float4 rv = *(const float4*)&rbuf[r][h];
            float4 wv = *(const float4*)&w[h];
            acc += rv.x * wv.x + rv.y * wv.y + rv.z * wv.z + rv.w * wv.w;
        }
        outc[(row0 + r) * OCC + oc] = acc + boc[oc];
    }
}

// ---------------------------------------------------------------------------
extern "C" void kernel_launch(void* const* d_in, const int* in_sizes, int n_in,
                              void* d_out, int out_size, void* d_ws, size_t ws_size,
                              hipStream_t stream)
{
    const float* x     = (const float*)d_in[0];
    const float* rate0 = (const float*)d_in[1];
    const float* noise = (const float*)d_in[2];
    const float* Wi    = (const float*)d_in[3];
    const float* bi    = (const float*)d_in[4];
    const float* Wh    = (const float*)d_in[5];
    const float* bh    = (const float*)d_in[6];
    const float* Wo    = (const float*)d_in[7];
    const float* bo    = (const float*)d_in[8];
    const float* Woc   = (const float*)d_in[9];
    const float* boc   = (const float*)d_in[10];

    float* out   = (float*)d_out;
    float* rateb = out + RATE_OFF;
    float* P     = (float*)d_ws;
    int*   flags = (int*)((char*)d_ws + FLAG_BYTE_OFF);

    hipMemsetAsync(flags, 0, FLAG_BYTES, stream);   // ws is not re-poisoned
    rnn_scan11<<<4 * BB, 1024, 0, stream>>>(x, rate0, noise, Wh, Wi, bi, bh,
                                            rateb, P, flags);
    readout<<<TT * BB / 16, 512, 0, stream>>>(rateb, Wo, bo, Woc, boc,
                                              out, out + OUT1_OFF);
}

// Round 12
// 4837.437 us; speedup vs baseline: 5.8380x; 1.1486x over previous
//
#include <hip/hip_runtime.h>
#include <math.h>

#define TT 2048
#define BB 64
#define II 64
#define HH 512
#define OO 32
#define OCC 8
#define QS 128   // k/h slice per WG (4-way split)
#define WT_LD 48 // padded leading dim of packed readout weights (32+8 -> 48)

// d_out layout: output [T,B,32] | output_ctx [T,B,8] | rate_all [T,B,512]
#define OUT1_OFF ((size_t)TT * BB * OO)
#define RATE_OFF (OUT1_OFF + (size_t)TT * BB * OCC)

// d_ws layout: P[B][4][2][HH] floats (1 MB) | flags @1MB (16KB) | Wt @2MB (96KB)
#define FLAG_BYTE_OFF ((size_t)1 << 20)
#define FLAG_BYTES (BB * 4 * 16 * sizeof(int))
#define WT_BYTE_OFF ((size_t)2 << 20)

// ---------------------------------------------------------------------------
// Pack Wt[h][o] = Wo[o][h] (o<32) / Woc[o-32][h] (32<=o<40) / 0 pad.
// Makes readout weight reads lane-consecutive (coalesced).
// ---------------------------------------------------------------------------
__global__ __launch_bounds__(256) void pack_wt(
    const float* __restrict__ Wo, const float* __restrict__ Woc,
    float* __restrict__ Wt)
{
    int idx = blockIdx.x * 256 + threadIdx.x;
    if (idx >= HH * WT_LD) return;
    int h = idx / WT_LD, o = idx % WT_LD;
    float v = 0.f;
    if (o < OO)            v = Wo[(size_t)o * HH + h];
    else if (o < OO + OCC) v = Woc[(size_t)(o - OO) * HH + h];
    Wt[idx] = v;
}

// ---------------------------------------------------------------------------
// Recurrent scan, 4-way k-split, prefold fused, round-9 flag sync.
// WG (q,b) at bid=q*64+b owns k-slice AND h-slice [128q,128q+128).
// 1024 threads: g=tid>>7 -> 16 k-rows, ht=tid&127 -> h-cols 4ht..4ht+3.
// SYNC RULES (hard-won):
//  - r8 hang: flag store and peer polls in DIFFERENT waves (tid 0 stores;
//    tid 64/128/192 poll). No store gated behind a poll.
//  - r10 storm: poll traffic O(pollers)=3/WG; consumers read remote P once.
//  - r4 storm: agent-scope RELAXED atomics only; ordering via B2's per-wave
//    vmcnt(0) drain before the flag store.
// r12 tweak: own-band P values are consumed locally -> not published (25%
// less store-ack traffic in the B2 drain).
// ---------------------------------------------------------------------------
__global__ __launch_bounds__(1024) void rnn_scan12(
    const float* __restrict__ x,       // [T,B,I]
    const float* __restrict__ rate0,   // [B,H]
    const float* __restrict__ noise,   // [T,B,H]
    const float* __restrict__ Wh,      // [H,H] row-major
    const float* __restrict__ Wi,      // [H,I]
    const float* __restrict__ bi,
    const float* __restrict__ bh,
    float* __restrict__ rate_out,      // [T,B,H]
    float* P,                          // [B][4][2][HH]
    int* flags)                        // [B*4*16]
{
    __shared__ float  st[QS];          // own state slice
    __shared__ float  parts[8 * HH];   // per-g partials (16 KB)
    __shared__ float4 wi4[II / 4][QS]; // Wi slice, [c4][l]
    __shared__ float4 xbuf4[II / 4];   // x_t

    const int bid = blockIdx.x;
    const int q   = bid >> 6;          // quarter 0..3
    const int b   = bid & 63;          // batch
    const int tid = threadIdx.x;
    const int g   = tid >> 7;          // 0..7 -> 16 k-rows each
    const int ht  = tid & 127;
    const int h4  = 4 * ht;
    const int kq  = q * QS + g * 16;

    const double SIG = 1.5 / sqrt(512.0);
    const float  NS  = (float)sqrt(2.0 * SIG * SIG / 0.1);

    // Wh weights fully register-resident: wreg[m] = W^T[kq+m][h4..h4+3]
    float4 wreg[16];
    #pragma unroll
    for (int m = 0; m < 16; ++m) {
        wreg[m].x = Wh[(size_t)(h4 + 0) * HH + kq + m];
        wreg[m].y = Wh[(size_t)(h4 + 1) * HH + kq + m];
        wreg[m].z = Wh[(size_t)(h4 + 2) * HH + kq + m];
        wreg[m].w = Wh[(size_t)(h4 + 3) * HH + kq + m];
    }

    // Wi rows of own h-slice -> LDS (one-time)
    for (int i = tid; i < QS * (II / 4); i += 1024) {
        int l = i >> 4, c4 = i & 15;
        wi4[c4][l] = *(const float4*)&Wi[(size_t)(q * QS + l) * II + 4 * c4];
    }

    const bool inband = (tid >= q * QS) && (tid < q * QS + QS);
    const int  l      = tid - q * QS;  // local h index when inband
    float rf = 0.f, bsum = 0.f;
    if (inband) {
        rf   = rate0[b * HH + tid];
        bsum = bi[tid] + bh[tid];
    }
    if (tid < QS) st[tid] = rate0[b * HH + q * QS + tid];
    int* myflag = &flags[(b * 4 + q) * 16];
    __syncthreads();

    for (int t = 0; t < TT; ++t) {
        const int par = t & 1;
        const size_t row = ((size_t)t * BB + b) * HH;

        // stage x_t (read after B1; next overwrite after B4)
        if (tid < II / 4)
            xbuf4[tid] = *(const float4*)&x[((size_t)t * BB + b) * II + 4 * tid];
        float nz = 0.f;
        if (inband) nz = noise[row + tid];    // early; hides under dot

        // ---- dot: this thread's 4 h-cols over its 16 k-rows (st broadcast)
        float a0 = 0.f, a1 = 0.f, a2 = 0.f, a3 = 0.f;
        #pragma unroll
        for (int mm = 0; mm < 4; ++mm) {
            float4 s4 = *(const float4*)&st[g * 16 + 4 * mm];
            a0 += wreg[4*mm].x*s4.x + wreg[4*mm+1].x*s4.y + wreg[4*mm+2].x*s4.z + wreg[4*mm+3].x*s4.w;
            a1 += wreg[4*mm].y*s4.x + wreg[4*mm+1].y*s4.y + wreg[4*mm+2].y*s4.z + wreg[4*mm+3].y*s4.w;
            a2 += wreg[4*mm].z*s4.x + wreg[4*mm+1].z*s4.y + wreg[4*mm+2].z*s4.z + wreg[4*mm+3].z*s4.w;
            a3 += wreg[4*mm].w*s4.x + wreg[4*mm+1].w*s4.y + wreg[4*mm+2].w*s4.z + wreg[4*mm+3].w*s4.w;
        }
        *(float4*)&parts[g * HH + h4] = make_float4(a0, a1, a2, a3);
        __syncthreads();                      // B1: parts + xbuf ready

        // ---- reduce over g; publish partial to IF (own band kept local)
        float s = 0.f;
        if (tid < HH) {
            #pragma unroll
            for (int p = 0; p < 8; ++p) s += parts[p * HH + tid];
            if (!inband)
                __hip_atomic_store(&P[(((size_t)b * 4 + q) * 2 + par) * HH + tid], s,
                                   __ATOMIC_RELAXED, __HIP_MEMORY_SCOPE_AGENT);
        }
        __syncthreads();                      // B2: all waves vmcnt(0) -> P at IF

        // ---- flag publish (wave 0, immediately after B2)
        if (tid == 0)
            __hip_atomic_store(myflag, t + 1, __ATOMIC_RELAXED,
                               __HIP_MEMORY_SCOPE_AGENT);

        // ---- fused prefold: hides under the poll window
        float pre = 0.f;
        if (inband) {
            pre = bsum + NS * nz;
            #pragma unroll
            for (int c4 = 0; c4 < II / 4; ++c4) {
                float4 wv = wi4[c4][l];
                float4 xv = xbuf4[c4];
                pre += wv.x * xv.x + wv.y * xv.y + wv.z * xv.z + wv.w * xv.w;
            }
        }

        // ---- peer polls (waves 1..3; store above precedes polls -- r8 rule)
        if (tid == 64 || tid == 128 || tid == 192) {
            int* f = &flags[(b * 4 + ((q + (tid >> 6)) & 3)) * 16];
            while (__hip_atomic_load(f, __ATOMIC_RELAXED,
                                     __HIP_MEMORY_SCOPE_AGENT) < t + 1) {}
        }
        __syncthreads();                      // B3: peers' P published

        // ---- consume: own-slice update (consumer reuses its own s)
        if (inband) {
            float tot = pre + s;
            #pragma unroll
            for (int j = 1; j < 4; ++j) {
                const int pj = (q + j) & 3;
                tot += __hip_atomic_load(
                    &P[(((size_t)b * 4 + pj) * 2 + par) * HH + tid],
                    __ATOMIC_RELAXED, __HIP_MEMORY_SCOPE_AGENT);
            }
            rf = 0.9f * rf + 0.1f * tanhf(tot);
            rate_out[row + tid] = rf;
            st[l] = rf;
        }
        __syncthreads();                      // B4: st ready for next dot
    }
}

// ---------------------------------------------------------------------------
// Readout with transposed weights: thread (r=tid>>5, o=tid&31) reads
// Wt[h*48+o] -- lanes read 32 CONSECUTIVE floats (one 128B line per wave
// instruction; upper half-wave broadcasts the same addresses). rbuf reads
// are LDS row-broadcasts. Fixes r11's 32-line-per-instruction scatter.
// ---------------------------------------------------------------------------
__global__ __launch_bounds__(512) void readout2(
    const float* __restrict__ rate_all,
    const float* __restrict__ Wt,   // [512][48] packed [Wo | Woc | pad]
    const float* __restrict__ bo, const float* __restrict__ boc,
    float* __restrict__ out, float* __restrict__ outc)
{
    __shared__ float rbuf[16][HH];
    const int tid  = threadIdx.x;
    const size_t row0 = (size_t)blockIdx.x * 16;

    for (int i = tid; i < 16 * (HH / 4); i += 512) {
        int r = i >> 7, c = (i & 127) * 4;
        *(float4*)&rbuf[r][c] = *(const float4*)&rate_all[(row0 + r) * HH + c];
    }
    __syncthreads();

    {
        const int r = tid >> 5, o = tid & 31;
        const float* wt = Wt + o;
        float acc = 0.f;
        #pragma unroll 8
        for (int h = 0; h < HH; h += 4) {
            float4 rv = *(const float4*)&rbuf[r][h];
            acc += rv.x * wt[(size_t)(h + 0) * WT_LD]
                 + rv.y * wt[(size_t)(h + 1) * WT_LD]
                 + rv.z * wt[(size_t)(h + 2) * WT_LD]
                 + rv.w * wt[(size_t)(h + 3) * WT_LD];
        }
        out[(row0 + r) * OO + o] = acc + bo[o];
    }
    if (tid < 128) {
        const int r = tid >> 3, c = tid & 7;
        const float* wt = Wt + OO + c;
        float acc = 0.f;
        #pragma unroll 8
        for (int h = 0; h < HH; h += 4) {
            float4 rv = *(const float4*)&rbuf[r][h];
            acc += rv.x * wt[(size_t)(h + 0) * WT_LD]
                 + rv.y * wt[(size_t)(h + 1) * WT_LD]
                 + rv.z * wt[(size_t)(h + 2) * WT_LD]
                 + rv.w * wt[(size_t)(h + 3) * WT_LD];
        }
        outc[(row0 + r) * OCC + c] = acc + boc[c];
    }
}

// ---------------------------------------------------------------------------
extern "C" void kernel_launch(void* const* d_in, const int* in_sizes, int n_in,
                              void* d_out, int out_size, void* d_ws, size_t ws_size,
                              hipStream_t stream)
{
    const float* x     = (const float*)d_in[0];
    const float* rate0 = (const float*)d_in[1];
    const float* noise = (const float*)d_in[2];
    const float* Wi    = (const float*)d_in[3];
    const float* bi    = (const float*)d_in[4];
    const float* Wh    = (const float*)d_in[5];
    const float* bh    = (const float*)d_in[6];
    const float* Wo    = (const float*)d_in[7];
    const float* bo    = (const float*)d_in[8];
    const float* Woc   = (const float*)d_in[9];
    const float* boc   = (const float*)d_in[10];

    float* out   = (float*)d_out;
    float* rateb = out + RATE_OFF;
    float* P     = (float*)d_ws;
    int*   flags = (int*)((char*)d_ws + FLAG_BYTE_OFF);
    float* Wt    = (float*)((char*)d_ws + WT_BYTE_OFF);

    hipMemsetAsync(flags, 0, FLAG_BYTES, stream);   // ws is not re-poisoned
    pack_wt<<<(HH * WT_LD + 255) / 256, 256, 0, stream>>>(Wo, Woc, Wt);
    rnn_scan12<<<4 * BB, 1024, 0, stream>>>(x, rate0, noise, Wh, Wi, bi, bh,
                                            rateb, P, flags);
    readout2<<<TT * BB / 16, 512, 0, stream>>>(rateb, Wt, bo, boc,
                                               out, out + OUT1_OFF);
}